// Round 8
// baseline (6557.967 us; speedup 1.0000x reference)
//
#include <hip/hip_runtime.h>
#include <cmath>

#define BATCH 128
#define TLEN  256
#define HDIM  1024
#define CDIM  10
#define NT    1024
#define NWG   256

typedef unsigned long long u64;
typedef unsigned int u32;

// h state, double buffered, k-major, u64 = 2 packed floats: g_hx[buf][j][b/2].
// ALL h accesses are relaxed agent-scope atomics (sc1) -> no cache fences;
// x/W/bias stay warm in L1/L2 across all 256 steps.
__device__ u64 g_hx[2][HDIM][BATCH / 2];

__device__ __forceinline__ float4 ld4(const float* p) { return *(const float4*)p; }

__device__ __forceinline__ u64 aload(const u64* p) {
    return __hip_atomic_load(p, __ATOMIC_RELAXED, __HIP_MEMORY_SCOPE_AGENT);
}
__device__ __forceinline__ void astore(u64* p, u64 v) {
    __hip_atomic_store(p, v, __ATOMIC_RELAXED, __HIP_MEMORY_SCOPE_AGENT);
}
__device__ __forceinline__ void astore32(u32* p, u32 v) {
    __hip_atomic_store(p, v, __ATOMIC_RELAXED, __HIP_MEMORY_SCOPE_AGENT);
}

// R13: LDS-only barrier (full lgkm drain) -- used OUTSIDE the phase loop.
__device__ __forceinline__ void barrier_lds() {
    asm volatile("s_waitcnt lgkmcnt(0)\n\ts_barrier" ::: "memory");
}

// Group barrier (R11/R12-proven): parallel arrivals on 128 distinct flags,
// per-wave self-release poll, monotonic targets, bounded spin.
// Keeps its explicit vmcnt(0): it is the h-publish release fence.
__device__ __forceinline__ void gbar2(u32* flags, int grp, int idx, u32 target) {
    asm volatile("s_waitcnt vmcnt(0)" ::: "memory");
    __syncthreads();
    if (threadIdx.x == 0)
        astore32(flags + grp * 128 + idx, target);
    const u64* base = (const u64*)(flags + grp * 128) + (threadIdx.x & 63);
    int guard = 0;
    for (;;) {
        const u64 v = aload(base);
        const bool ok = ((u32)v >= target) && ((u32)(v >> 32) >= target);
        if (__all(ok) || ++guard > (1 << 20)) break;
        __builtin_amdgcn_s_sleep(1);
    }
}

#define FMA4(d, s, v) do { (d).x = fmaf((s), (v).x, (d).x); (d).y = fmaf((s), (v).y, (d).y); \
                           (d).z = fmaf((s), (v).z, (d).z); (d).w = fmaf((s), (v).w, (d).w); } while (0)
#define ADD4(d, s)     do { (d).x += (s).x; (d).y += (s).y; (d).z += (s).z; (d).w += (s).w; } while (0)

// R18: counted-drain phases. lgkmcnt is IN-ORDER, so any in-phase-consumed read
// issued AFTER the prefetch forces a full drain (R17's bug). Fix: issue order
// [ds_write][w0,w1][hAn,hBn prefetch][FMAs][lgkmcnt(2); s_barrier], pinned by
// sched_barrier(0). The FMA wait (needs w1) becomes lgkmcnt(2) -> the 2 h-
// prefetch reads FLY ACROSS the barrier and land during next phase's FMAs.
// 3 h-buffers make this race-free WITHOUT assuming LDS queue FIFO:
//   - phase p writes buf (p+2)%3; its last readers were phase p-2's prefetch
//     (chunk p-1), consumed by phase p-1's FMAs (compiler-counted wait) ->
//     complete before phase p-1's barrier -> one full barrier before the write.
//   - in-flight-at-barrier reads target buf (p+1)%3; next phase writes buf
//     (p+3)%3 = p%3 != (p+1)%3. QED.
__global__ void __launch_bounds__(NT, 1)
lstm_fused(const float* __restrict__ x,
           const float* __restrict__ Wgx, const float* __restrict__ Wgh, const float* __restrict__ bg,
           const float* __restrict__ Wix, const float* __restrict__ Wih, const float* __restrict__ bi,
           const float* __restrict__ Wfx, const float* __restrict__ Wfh, const float* __restrict__ bf,
           const float* __restrict__ Wox, const float* __restrict__ Woh, const float* __restrict__ bo,
           const float* __restrict__ Wph, const float* __restrict__ bp,
           u32* __restrict__ flags, float* __restrict__ out)
{
    __shared__ float sW[8][HDIM][4];            // [j_local][k][gate], 128 KB
    __shared__ __align__(16) float sHraw[3 * 32 * 68];   // h TRIPLE buf, 26.1 KB; sS aliases bufs 0-1

    const int tid  = threadIdx.x;
    const int wave = tid >> 6;          // 0..15
    const int jq   = wave >> 2;         // j-pair index (0..3)
    const int kh   = wave & 3;          // k-quarter within chunk
    const int lane = tid & 63;
    const int ks   = lane & 7;
    const int bo8  = lane >> 3;
    const int rgB  = blockIdx.x >> 1;   // j in [8*rgB, 8*rgB+8)  == index in group
    const int bgB  = blockIdx.x & 1;    // b in [64*bgB, 64*bgB+64) == group id

    // ---- stage W once, gate-interleaved (1024 threads: 4 rows per pass) ----
    {
        auto stageW = [&](const float* Wsrc, int g) {
            #pragma unroll
            for (int it = 0; it < 2; ++it) {
                const int row = it * 4 + (tid >> 8);     // 0..7
                const int c4  = tid & 255;               // float4 column
                const float4 v = ld4(Wsrc + (size_t)(rgB * 8 + row) * HDIM + c4 * 4);
                sW[row][c4 * 4 + 0][g] = v.x;
                sW[row][c4 * 4 + 1][g] = v.y;
                sW[row][c4 * 4 + 2][g] = v.z;
                sW[row][c4 * 4 + 3][g] = v.w;
            }
        };
        stageW(Wgh, 0); stageW(Wih, 1); stageW(Wfh, 2); stageW(Woh, 3);
    }

    // epilogue cells: j = rgB*8 + jq*2 + (ks>>2); b = bgB*64 + bo8*8 + (ks&3)*2 + cell.
    const int jc = rgB * 8 + jq * 2 + (ks >> 2);
    const float4 wx4 = make_float4(Wgx[jc], Wix[jc], Wfx[jc], Wox[jc]);
    const float4 b4  = make_float4(bg[jc], bi[jc], bf[jc], bo[jc]);
    const int bloc = bgB * 64 + bo8 * 8 + (ks & 3) * 2;   // cell-0 batch index
    float cst = 0.f;                                       // my cell's c-state

    // zero h0 -- OWN b-half only: 8 j-rows x 32 u64
    if (tid < 256)
        astore(&g_hx[0][rgB * 8 + (tid >> 5)][bgB * 32 + (tid & 31)], 0ull);

    gbar2(flags, bgB, rgB, 1u);

    const int skc = tid >> 5;                   // staging: k within chunk (0..31)
    const int sbu = tid & 31;                   // staging: u64 col within 32
    const int hb0 = bgB * 32 + sbu;             // staging: u64 offset in g_hx row
    const int swoff = skc * 34 + sbu;           // u64 slot inside a buffer
    const int kc_ = kh * 8 + ks;                // this lane's k within any chunk

    // PH(P, G): [1] ds_write chunk P+2 (= G) into buf (P+2)%3 (base bwU);
    // [2] w0/w1 reads (in-phase, broadcast, conflict-free); [3] prefetch chunk
    // P+1 operands from buf (P+1)%3 (base bnF); [4] reissue G = chunk P+4;
    // [5] FMA chunk P from hAc/hBc (identical sequence to proven COMP);
    // [6] counted drain + barrier; swap regs; advance rolling bases.
#define PH(P, G)                                                                \
    {                                                                           \
        if ((P) + 2 < 32) ((u64*)sHraw)[bwU + swoff] = G;                       \
        __builtin_amdgcn_sched_barrier(0);                                      \
        const float4 w0 = ld4(&sW[jq * 2 + 0][(P) * 32 + kc_][0]);              \
        const float4 w1 = ld4(&sW[jq * 2 + 1][(P) * 32 + kc_][0]);              \
        __builtin_amdgcn_sched_barrier(0);                                      \
        if ((P) + 1 < 32) {                                                     \
            const float* pp_ = &sHraw[bnF + kc_ * 68 + bo8 * 8];                \
            hAn = ld4(pp_); hBn = ld4(pp_ + 4);                                 \
        }                                                                       \
        if ((P) + 4 < 32) G = aload(hrow + (size_t)((P) + 4) * 2048);           \
        __builtin_amdgcn_sched_barrier(0);                                      \
        FMA4(acc[0][0], hAc.x, w0); FMA4(acc[0][1], hAc.y, w0);                 \
        FMA4(acc[0][2], hAc.z, w0); FMA4(acc[0][3], hAc.w, w0);                 \
        FMA4(acc[0][4], hBc.x, w0); FMA4(acc[0][5], hBc.y, w0);                 \
        FMA4(acc[0][6], hBc.z, w0); FMA4(acc[0][7], hBc.w, w0);                 \
        FMA4(acc[1][0], hAc.x, w1); FMA4(acc[1][1], hAc.y, w1);                 \
        FMA4(acc[1][2], hAc.z, w1); FMA4(acc[1][3], hAc.w, w1);                 \
        FMA4(acc[1][4], hBc.x, w1); FMA4(acc[1][5], hBc.y, w1);                 \
        FMA4(acc[1][6], hBc.z, w1); FMA4(acc[1][7], hBc.w, w1);                 \
        asm volatile("s_waitcnt lgkmcnt(2)\n\ts_barrier" ::: "memory");         \
        hAc = hAn; hBc = hBn;                                                   \
        bwU += 1088; if (bwU >= 3264) bwU -= 3264;                              \
        bnF += 2176; if (bnF >= 6528) bnF -= 6528;                              \
    }

    for (int t = 0; t < TLEN; ++t) {
        const u64* hc = &g_hx[t & 1][0][0];
        u32*       hn32 = (u32*)&g_hx[(t + 1) & 1][0][0];

        const u64* hrow = hc + (size_t)skc * 64 + hb0;
        // prologue: stage chunks 0 (buf0), 1 (buf1); preload A,B = chunks 2,3
        {
            const u64 g0 = aload(hrow);
            const u64 g1 = aload(hrow + 2048);
            ((u64*)sHraw)[swoff]        = g0;
            ((u64*)sHraw)[1088 + swoff] = g1;
        }
        u64 A = aload(hrow + 2 * 2048);
        u64 B = aload(hrow + 3 * 2048);

        // x for my epilogue cell (kh0 -> b, kh2 -> b+1), L1-warm
        float xv = 0.f;
        if ((kh & 1) == 0)
            xv = x[(size_t)(bloc + (kh >> 1)) * TLEN + t];

        barrier_lds();                  // staging writes drained; A,B,x in flight

        // chunk-0 reg load (buf0). Safe without extra barrier: phase 0 writes
        // buf2; these reads complete before phase-0 FMAs via compiler wait.
        float4 hAc, hBc;
        {
            const float* h0p_ = &sHraw[kc_ * 68 + bo8 * 8];
            hAc = ld4(h0p_); hBc = ld4(h0p_ + 4);
        }
        float4 hAn = make_float4(0.f, 0.f, 0.f, 0.f);
        float4 hBn = make_float4(0.f, 0.f, 0.f, 0.f);
        int bwU = 2176;                 // u64 base: phase-0 write buf = buf2
        int bnF = 2176;                 // float base: phase-0 prefetch buf = buf1

        float4 acc[2][8];   // [j_local][b]; components = 4 gates. STATIC indices only.
        #pragma unroll
        for (int jl = 0; jl < 2; ++jl)
            #pragma unroll
            for (int cb = 0; cb < 8; ++cb)
                acc[jl][cb] = make_float4(0.f, 0.f, 0.f, 0.f);

        #pragma unroll 1
        for (int cc = 0; cc < 16; ++cc) {
            const int e0 = cc * 2;
            PH(e0,     A);
            PH(e0 + 1, B);
        }
        // after phase 31: no lgkm ops outstanding (30's prefetch consumed by
        // 31's FMAs; 31 issued none) -> sS alias of bufs 0-1 is safe.

        // ---- intra-wave recursive-halving reduction over ks (56 shfl) ----
        float4 r1[8];
        #pragma unroll
        for (int i = 0; i < 8; ++i) {
            const float4 fs = (ks & 4) ? acc[0][i] : acc[1][i];
            float4 fr;
            fr.x = __shfl_xor(fs.x, 4); fr.y = __shfl_xor(fs.y, 4);
            fr.z = __shfl_xor(fs.z, 4); fr.w = __shfl_xor(fs.w, 4);
            const float4 fk = (ks & 4) ? acc[1][i] : acc[0][i];
            r1[i] = make_float4(fk.x + fr.x, fk.y + fr.y, fk.z + fr.z, fk.w + fr.w);
        }
        float4 r2[4];
        #pragma unroll
        for (int i = 0; i < 4; ++i) {
            const float4 fs = (ks & 2) ? r1[i] : r1[i + 4];
            float4 fr;
            fr.x = __shfl_xor(fs.x, 2); fr.y = __shfl_xor(fs.y, 2);
            fr.z = __shfl_xor(fs.z, 2); fr.w = __shfl_xor(fs.w, 2);
            const float4 fk = (ks & 2) ? r1[i + 4] : r1[i];
            r2[i] = make_float4(fk.x + fr.x, fk.y + fr.y, fk.z + fr.z, fk.w + fr.w);
        }
        float4 q0, q1;
        {
            const float4 fs0 = (ks & 1) ? r2[0] : r2[2];
            const float4 fs1 = (ks & 1) ? r2[1] : r2[3];
            float4 fr0, fr1;
            fr0.x = __shfl_xor(fs0.x, 1); fr0.y = __shfl_xor(fs0.y, 1);
            fr0.z = __shfl_xor(fs0.z, 1); fr0.w = __shfl_xor(fs0.w, 1);
            fr1.x = __shfl_xor(fs1.x, 1); fr1.y = __shfl_xor(fs1.y, 1);
            fr1.z = __shfl_xor(fs1.z, 1); fr1.w = __shfl_xor(fs1.w, 1);
            const float4 fk0 = (ks & 1) ? r2[2] : r2[0];
            const float4 fk1 = (ks & 1) ? r2[3] : r2[1];
            q0 = make_float4(fk0.x + fr0.x, fk0.y + fr0.y, fk0.z + fr0.z, fk0.w + fr0.w);
            q1 = make_float4(fk1.x + fr1.x, fk1.y + fr1.y, fk1.z + fr1.z, fk1.w + fr1.w);
        }
        // q0,q1 = partial (this kh) preacts for cells (jc, bloc) and (jc, bloc+1)

        // ---- cross-kh reduction via LDS aliased onto dead sH (bufs 0-1) ----
        float4* sS = (float4*)sHraw;    // 1024 f4 = 16 KB <= 17.4 KB (bufs 0-1)
        if (kh & 1) {                   // kh1 -> slot(jq,0), kh3 -> slot(jq,1)
            const int sl = ((jq * 2 + (kh >> 1)) * 64 + lane) * 2;
            sS[sl]     = q0;
            sS[sl + 1] = q1;
        }
        barrier_lds();
        if ((kh & 1) == 0) {            // kh0 adds kh1; kh2 adds kh3
            const int sl = ((jq * 2 + (kh >> 1)) * 64 + lane) * 2;
            ADD4(q0, sS[sl]);
            ADD4(q1, sS[sl + 1]);
        }
        // stage 2: kh0 surrenders q1, kh2 surrenders q0 (each keeps its cell)
        if (kh == 0) sS[((jq * 2 + 0) * 64 + lane) * 2 + 1] = q1;
        if (kh == 2) sS[((jq * 2 + 1) * 64 + lane) * 2 + 0] = q0;
        barrier_lds();

        if ((kh & 1) == 0) {
            float4 qq;
            if (kh == 0) {
                ADD4(q0, sS[((jq * 2 + 1) * 64 + lane) * 2 + 0]);
                qq = q0;
            } else {
                ADD4(q1, sS[((jq * 2 + 0) * 64 + lane) * 2 + 1]);
                qq = q1;
            }
            FMA4(qq, xv, wx4);
            qq.x += b4.x; qq.y += b4.y; qq.z += b4.z; qq.w += b4.w;
            const float g_ = tanhf(qq.x);
            const float i_ = 1.f / (1.f + expf(-qq.y));
            const float f_ = 1.f / (1.f + expf(-qq.z));
            const float o_ = 1.f / (1.f + expf(-qq.w));
            cst = g_ * i_ + cst * f_;
            const float hv = tanhf(cst) * o_;
            u32 bits; __builtin_memcpy(&bits, &hv, 4);
            astore32(hn32 + (size_t)jc * 128 + bloc + (kh >> 1), bits);
        }

        gbar2(flags, bgB, rgB, (u32)(t + 2));
    } // t
#undef PH

    // ---- final projection: out = h_final @ W_ph + bias_p (final h in buf 0).
    // Group-confinement: block projects b = bgB*64 + rgB (own b-half).
    if (rgB < 64) {
        const int b = bgB * 64 + rgB;
        float part[CDIM];
        #pragma unroll
        for (int c2 = 0; c2 < CDIM; ++c2) part[c2] = 0.f;
        for (int k = tid; k < HDIM; k += NT) {
            const u64 hvu = aload(&g_hx[0][k][b >> 1]);
            float2 hv2; __builtin_memcpy(&hv2, &hvu, 8);
            const float hvv = (b & 1) ? hv2.y : hv2.x;
            #pragma unroll
            for (int c2 = 0; c2 < CDIM; ++c2)
                part[c2] = fmaf(hvv, Wph[(size_t)k * CDIM + c2], part[c2]);
        }
        float* red = (float*)&sW[0][0][0];   // reuse dead W LDS (48 KB needed)
        #pragma unroll
        for (int c2 = 0; c2 < CDIM; ++c2) red[tid * 12 + c2] = part[c2];
        __syncthreads();
        for (int s = NT / 2; s > 0; s >>= 1) {
            if (tid < s) {
                #pragma unroll
                for (int c2 = 0; c2 < CDIM; ++c2)
                    red[tid * 12 + c2] += red[(tid + s) * 12 + c2];
            }
            __syncthreads();
        }
        if (tid < CDIM) out[(size_t)b * CDIM + tid] = red[tid] + bp[tid];
    }
}

extern "C" void kernel_launch(void* const* d_in, const int* in_sizes, int n_in,
                              void* d_out, int out_size, void* d_ws, size_t ws_size,
                              hipStream_t stream) {
    const float* x   = (const float*)d_in[0];
    const float* Wgx = (const float*)d_in[1];
    const float* Wgh = (const float*)d_in[2];
    const float* bg  = (const float*)d_in[3];
    const float* Wix = (const float*)d_in[4];
    const float* Wih = (const float*)d_in[5];
    const float* bi  = (const float*)d_in[6];
    const float* Wfx = (const float*)d_in[7];
    const float* Wfh = (const float*)d_in[8];
    const float* bf  = (const float*)d_in[9];
    const float* Wox = (const float*)d_in[10];
    const float* Woh = (const float*)d_in[11];
    const float* bo  = (const float*)d_in[12];
    const float* Wph = (const float*)d_in[13];
    const float* bp  = (const float*)d_in[14];
    u32* flags = (u32*)d_ws;               // u32[2][128] monotonic arrival flags
    float* out = (float*)d_out;

    (void)hipMemsetAsync(d_ws, 0, 2 * 128 * sizeof(u32), stream);   // capturable node

    void* args[] = {&x, &Wgx, &Wgh, &bg, &Wix, &Wih, &bi, &Wfx, &Wfh, &bf,
                    &Wox, &Woh, &bo, &Wph, &bp, &flags, &out};
    hipError_t rc = hipLaunchCooperativeKernel((void*)lstm_fused, dim3(NWG), dim3(NT),
                                               args, 0, stream);
    if (rc != hipSuccess) {
        // Custom barrier needs no cooperative-runtime support; 256 blocks at
        // 1 block/CU are fully co-resident under a regular launch too.
        lstm_fused<<<dim3(NWG), dim3(NT), 0, stream>>>(
            x, Wgx, Wgh, bg, Wix, Wih, bi, Wfx, Wfh, bf,
            Wox, Woh, bo, Wph, bp, flags, out);
    }
}